// Round 1
// 1615.325 us; speedup vs baseline: 1.1715x; 1.1715x over previous
//
#include <hip/hip_runtime.h>
#include <stdint.h>

#define B_    16
#define D_IN_ 1024
#define T_    1024
#define K_    8192
#define D_CB_ 256
#define NTOK  (B_*T_)   // 16384

typedef unsigned long long ull;
typedef __attribute__((ext_vector_type(8))) short short8;   // 8 bf16 (4 VGPRs)
typedef __attribute__((ext_vector_type(4))) float f32x4;

// ---- workspace layout (float offsets) ----
#define WS_WIN   0            // w_in  [256][1024]
#define WS_WOUT  262144       // w_out [1024][256]
#define WS_ENC   524288       // enc   [16384][256] (token-major z_e)
#define WS_INVE  4718592      // [16384]
#define WS_ESQ   4734976      // [16384]
#define WS_INVC  4751360      // [8192]
#define WS_CSQ   4759552      // [8192]
#define WS_KEYS  4767744      // u64 [16384] (argmin packed keys) = 32768 floats
#define WS_CNT   4800512      // [8192] counts (float)
#define WS_LOSS  4808704      // [16] per-batch sq-err sums

// ---- output layout (float offsets) ----
#define OUT_ZQ   0
#define OUT_IDX  16777216
#define OUT_COMM 16793600
#define OUT_CB   16793616
#define OUT_DIST 16793632
#define OUT_PERP 151011360
#define OUT_ACT  151011361

// ---- scratch carved out of OUT_ZQ (fully overwritten by out_gemm at the end) ----
// float offsets relative to out+OUT_ZQ
#define SCR_EHI  0            // ushort[16384*256] hi bf16 of enc_n  (2,097,152 floats)
#define SCR_ELO  2097152      // ushort[16384*256] lo
#define SCR_CHI  4194304      // ushort[8192*256]  hi bf16 of cb_n   (1,048,576 floats)
#define SCR_CLO  5242880      // ushort[8192*256]  lo
#define SCR_MINB 6291456      // ull  [16384][64][2]  per (row, colblock) min1/min2 (4,194,304 floats)
#define SCR_FLAG 10485760     // int  [16384]
// ends at 10,502,144 floats < 16,777,216 (OUT_ZQ size)  -> safe

#define MARGIN 2.5e-4f        // bf16x3 dist error bound ~2e-5; 12x safety

__device__ __forceinline__ float wave_sum(float s) {
    for (int o = 32; o; o >>= 1) s += __shfl_down(s, o, 64);
    return s;
}

__device__ __forceinline__ unsigned short f2bf(float f) {   // RNE fp32 -> bf16
    unsigned u = __float_as_uint(f);
    return (unsigned short)((u + 0x7fffu + ((u >> 16) & 1u)) >> 16);
}

// weight_norm dim=0: w[r][c] = g[r]*v[r][c]/||v[r]||
__global__ void wn_kernel(const float* __restrict__ g, const float* __restrict__ v,
                          float* __restrict__ w, int rows, int cols) {
    int wave = threadIdx.x >> 6, lane = threadIdx.x & 63;
    int row = blockIdx.x * 4 + wave;
    if (row >= rows) return;
    const float* vr = v + (size_t)row * cols;
    float s = 0.f;
    for (int c = lane; c < (cols >> 2); c += 64) {
        float4 x = ((const float4*)vr)[c];
        s += x.x*x.x + x.y*x.y + x.z*x.z + x.w*x.w;
    }
    s = wave_sum(s);
    s = __shfl(s, 0, 64);
    float norm = sqrtf(s);
    float gr = g[row];
    float* wr = w + (size_t)row * cols;
    for (int c = lane; c < cols; c += 64)
        wr[c] = gr * vr[c] / norm;
}

// per-row (256-col) l2 stats + bf16 hi/lo split of the normalized row
__global__ void split_kernel(const float* __restrict__ x, float* __restrict__ inv,
                             float* __restrict__ sq, unsigned short* __restrict__ hi,
                             unsigned short* __restrict__ lo) {
    int wave = threadIdx.x >> 6, lane = threadIdx.x & 63;
    int row = blockIdx.x * 4 + wave;
    float4 v = ((const float4*)(x + (size_t)row * D_CB_))[lane];
    float s = v.x*v.x + v.y*v.y + v.z*v.z + v.w*v.w;
    s = wave_sum(s);
    s = __shfl(s, 0, 64);
    float n = fmaxf(sqrtf(s), 1e-12f);
    float iv = 1.0f / n;
    if (lane == 0) { inv[row] = iv; sq[row] = s * iv * iv; }
    float f[4] = { v.x*iv, v.y*iv, v.z*iv, v.w*iv };
    unsigned short h[4], l[4];
    #pragma unroll
    for (int i = 0; i < 4; ++i) {
        h[i] = f2bf(f[i]);
        float hf = __uint_as_float((unsigned)h[i] << 16);
        l[i] = f2bf(f[i] - hf);
    }
    *(ushort4*)(hi + (size_t)row * D_CB_ + lane * 4) = make_ushort4(h[0], h[1], h[2], h[3]);
    *(ushort4*)(lo + (size_t)row * D_CB_ + lane * 4) = make_ushort4(l[0], l[1], l[2], l[3]);
}

// z_e GEMM: enc[b*T+t][o] = sum_i w_in[o][i]*z[b][i][t] + in_b[o]
__global__ __launch_bounds__(256) void ze_gemm(const float* __restrict__ w,
        const float* __restrict__ z, const float* __restrict__ bias,
        float* __restrict__ enc) {
    __shared__ float As[32 * 68];
    __shared__ float Bs[32 * 68];
    int b  = blockIdx.z;
    int o0 = blockIdx.y * 64;
    int t0 = blockIdx.x * 64;
    int t  = threadIdx.x;
    int tx = t & 15, ty = t >> 4;
    float acc[4][4] = {};
    const float* zb = z + (size_t)b * D_IN_ * T_;
    for (int kt = 0; kt < D_IN_ / 32; ++kt) {
        #pragma unroll
        for (int p = 0; p < 2; ++p) {
            int q = p * 256 + t;
            int r = q >> 3, c4 = q & 7;
            float4 x = *(const float4*)&w[(size_t)(o0 + r) * D_IN_ + kt * 32 + c4 * 4];
            As[(c4*4+0)*68 + r] = x.x; As[(c4*4+1)*68 + r] = x.y;
            As[(c4*4+2)*68 + r] = x.z; As[(c4*4+3)*68 + r] = x.w;
        }
        #pragma unroll
        for (int p = 0; p < 2; ++p) {
            int q = p * 256 + t;
            int r = q >> 4, c4 = q & 15;
            float4 x = *(const float4*)&zb[(size_t)(kt * 32 + r) * T_ + t0 + c4 * 4];
            *(float4*)&Bs[r * 68 + c4 * 4] = x;
        }
        __syncthreads();
        #pragma unroll 4
        for (int k = 0; k < 32; ++k) {
            float a[4], bv[4];
            *(float4*)a  = *(float4*)&As[k * 68 + tx * 4];
            *(float4*)bv = *(float4*)&Bs[k * 68 + ty * 4];
            #pragma unroll
            for (int i = 0; i < 4; ++i)
                #pragma unroll
                for (int j = 0; j < 4; ++j)
                    acc[i][j] = fmaf(a[j], bv[i], acc[i][j]);
        }
        __syncthreads();
    }
    float bias4[4];
    *(float4*)bias4 = *(const float4*)&bias[o0 + tx * 4];
    #pragma unroll
    for (int i = 0; i < 4; ++i) {
        int token = b * T_ + t0 + ty * 4 + i;
        float4 v = make_float4(acc[i][0] + bias4[0], acc[i][1] + bias4[1],
                               acc[i][2] + bias4[2], acc[i][3] + bias4[3]);
        *(float4*)&enc[(size_t)token * D_CB_ + o0 + tx * 4] = v;
    }
}

// dist GEMM via bf16x3 MFMA: dist[row][col] = esq[row] + csq[col] - 2*(hh+hl+lh)
// 128x128 tile / block, 4 waves (2x2), 64x64 per wave, direct-from-L2 fragment loads.
// Also emits per-(row, colblock) packed (min1,min2) keys for exact-argmin repair.
__global__ __launch_bounds__(256, 3) void dist_mfma(
        const unsigned short* __restrict__ ehi, const unsigned short* __restrict__ elo,
        const unsigned short* __restrict__ chi, const unsigned short* __restrict__ clo,
        const float* __restrict__ esq, const float* __restrict__ csq,
        float* __restrict__ dist, ull* __restrict__ minb) {
    __shared__ ull pairs[2][64][2][2];
    int bid = blockIdx.x;
    int lin = (bid & 7) * 1024 + (bid >> 3);   // XCD-aware swizzle (8192 % 8 == 0)
    int bx = lin >> 7;                          // col block 0..63 (8 per XCD -> B panel L2-resident)
    int by = lin & 127;                         // row block 0..127
    int r0 = by * 128, c0 = bx * 128;
    int t = threadIdx.x;
    int wave = t >> 6, lane = t & 63;
    int wm = wave >> 1, wn = wave & 1;
    int lr = lane & 15, kg = lane >> 4;

    const unsigned short* ea = ehi + (size_t)(r0 + wm*64 + lr) * D_CB_ + kg*8;
    const unsigned short* eb = elo + (size_t)(r0 + wm*64 + lr) * D_CB_ + kg*8;
    const unsigned short* ca = chi + (size_t)(c0 + wn*64 + lr) * D_CB_ + kg*8;
    const unsigned short* cl = clo + (size_t)(c0 + wn*64 + lr) * D_CB_ + kg*8;

    f32x4 acc[4][4] = {};
    for (int kt = 0; kt < D_CB_ / 32; ++kt) {
        short8 ah[4], al[4], bh[4], bl[4];
        int k = kt * 32;
        #pragma unroll
        for (int i = 0; i < 4; ++i) {
            ah[i] = *(const short8*)(ea + (size_t)i*16*D_CB_ + k);
            al[i] = *(const short8*)(eb + (size_t)i*16*D_CB_ + k);
            bh[i] = *(const short8*)(ca + (size_t)i*16*D_CB_ + k);
            bl[i] = *(const short8*)(cl + (size_t)i*16*D_CB_ + k);
        }
        #pragma unroll
        for (int i = 0; i < 4; ++i)
            #pragma unroll
            for (int j = 0; j < 4; ++j) {
                acc[i][j] = __builtin_amdgcn_mfma_f32_16x16x32_bf16(ah[i], bh[j], acc[i][j], 0, 0, 0);
                acc[i][j] = __builtin_amdgcn_mfma_f32_16x16x32_bf16(ah[i], bl[j], acc[i][j], 0, 0, 0);
                acc[i][j] = __builtin_amdgcn_mfma_f32_16x16x32_bf16(al[i], bh[j], acc[i][j], 0, 0, 0);
            }
    }
    float csqv[4];
    #pragma unroll
    for (int j = 0; j < 4; ++j) csqv[j] = csq[c0 + wn*64 + j*16 + lr];
    // D layout (m89-verified): col = lane&15, row = (lane>>4)*4 + reg
    #pragma unroll
    for (int i = 0; i < 4; ++i) {
        #pragma unroll
        for (int r = 0; r < 4; ++r) {
            int rl = i*16 + kg*4 + r;
            int grow = r0 + wm*64 + rl;
            float es = esq[grow];
            float* drow = dist + (size_t)grow * K_ + c0 + wn*64 + lr;
            ull m1 = ~0ull, m2 = ~0ull;
            #pragma unroll
            for (int j = 0; j < 4; ++j) {
                float d = fmaf(-2.0f, acc[i][j][r], es + csqv[j]);
                drow[j*16] = d;
                ull key = ((ull)__float_as_uint(d) << 32) | (unsigned)(c0 + wn*64 + j*16 + lr);
                if (key < m1) { m2 = m1; m1 = key; } else if (key < m2) m2 = key;
            }
            #pragma unroll
            for (int off = 1; off < 16; off <<= 1) {   // 2-min butterfly within 16-lane col group
                ull o1 = __shfl_xor(m1, off, 64);
                ull o2 = __shfl_xor(m2, off, 64);
                ull n1 = o1 < m1 ? o1 : m1;
                ull x  = o1 < m1 ? m1 : o1;
                ull y  = o2 < m2 ? o2 : m2;
                m2 = x < y ? x : y;
                m1 = n1;
            }
            if (lr == 0) { pairs[wm][rl][wn][0] = m1; pairs[wm][rl][wn][1] = m2; }
        }
    }
    __syncthreads();
    if (t < 128) {
        int wm2 = t >> 6, rl = t & 63;
        ull a1 = pairs[wm2][rl][0][0], a2 = pairs[wm2][rl][0][1];
        ull b1 = pairs[wm2][rl][1][0], b2 = pairs[wm2][rl][1][1];
        ull m1 = a1 < b1 ? a1 : b1;
        ull x  = a1 < b1 ? b1 : a1;
        ull y  = a2 < b2 ? a2 : b2;
        ull m2 = x < y ? x : y;
        size_t grow = (size_t)(r0 + wm2*64 + rl);
        minb[(grow*64 + bx)*2 + 0] = m1;
        minb[(grow*64 + bx)*2 + 1] = m2;
    }
}

// reduce per-block min pairs -> keys[row]; flag rows whose 1st-2nd gap < MARGIN
__global__ void minreduce(const ull* __restrict__ minb, ull* __restrict__ keys,
                          int* __restrict__ flags) {
    int wave = threadIdx.x >> 6, lane = threadIdx.x & 63;
    int row = blockIdx.x * 4 + wave;
    ull m1 = minb[((size_t)row*64 + lane)*2 + 0];
    ull m2 = minb[((size_t)row*64 + lane)*2 + 1];
    #pragma unroll
    for (int off = 1; off < 64; off <<= 1) {
        ull o1 = __shfl_xor(m1, off, 64);
        ull o2 = __shfl_xor(m2, off, 64);
        ull n1 = o1 < m1 ? o1 : m1;
        ull x  = o1 < m1 ? m1 : o1;
        ull y  = o2 < m2 ? o2 : m2;
        m2 = x < y ? x : y;
        m1 = n1;
    }
    if (lane == 0) {
        keys[row] = m1;
        float d1 = __uint_as_float((unsigned)(m1 >> 32));
        float d2 = __uint_as_float((unsigned)(m2 >> 32));
        flags[row] = (d2 - d1 < MARGIN) ? 1 : 0;
    }
}

// exact fp32 argmin repair for flagged rows: rescan dist row, recompute all
// candidates within MARGIN of the observed min exactly, keep first-smallest.
__global__ void argmin_fix(const float* __restrict__ enc, const float* __restrict__ inve,
        const float* __restrict__ esq, const float* __restrict__ cb,
        const float* __restrict__ invc, const float* __restrict__ csq,
        const float* __restrict__ dist, const int* __restrict__ flags,
        ull* __restrict__ keys) {
    int row = blockIdx.x;
    if (!flags[row]) return;
    int lane = threadIdx.x;
    ull k0 = keys[row];
    float thr = __uint_as_float((unsigned)(k0 >> 32)) + MARGIN;
    float iv = inve[row];
    float4 ev = ((const float4*)(enc + (size_t)row * D_CB_))[lane];
    ev.x *= iv; ev.y *= iv; ev.z *= iv; ev.w *= iv;
    float es = esq[row];
    float best = 1e30f; int bestc = 0;
    for (int base = 0; base < K_; base += 64) {
        float d = dist[(size_t)row * K_ + base + lane];
        ull mask = __ballot(d <= thr);
        while (mask) {
            int b = __ffsll(mask) - 1;
            mask &= mask - 1;
            int c = base + b;
            float4 cv = ((const float4*)(cb + (size_t)c * D_CB_))[lane];
            float p = ev.x*cv.x + ev.y*cv.y + ev.z*cv.z + ev.w*cv.w;
            p = wave_sum(p);
            p = __shfl(p, 0, 64);
            float dx = fmaf(-2.0f * invc[c], p, es + csq[c]);
            if (dx < best) { best = dx; bestc = c; }   // ascending c => first-min on ties
        }
    }
    if (lane == 0)
        keys[row] = ((ull)__float_as_uint(best) << 32) | (unsigned)bestc;
}

// per-token: indices, (z_e - z_q)^2 partial sums, histogram
__global__ void token_kernel(const float* __restrict__ enc, const float* __restrict__ cb,
        const ull* __restrict__ keys, float* __restrict__ idx_out,
        float* __restrict__ counts, float* __restrict__ loss) {
    int wave = threadIdx.x >> 6, lane = threadIdx.x & 63;
    int tok = blockIdx.x * 4 + wave;
    int idx = (int)(unsigned int)(keys[tok] & 0xffffffffull);
    float4 e = ((const float4*)(enc + (size_t)tok * D_CB_))[lane];
    float4 q = ((const float4*)(cb  + (size_t)idx * D_CB_))[lane];
    float dx = e.x - q.x, dy = e.y - q.y, dz = e.z - q.z, dw = e.w - q.w;
    float s = dx*dx + dy*dy + dz*dz + dw*dw;
    s = wave_sum(s);
    if (lane == 0) {
        idx_out[tok] = (float)idx;
        atomicAdd(&counts[idx], 1.0f);
        atomicAdd(&loss[tok >> 10], s);
    }
}

// out GEMM: z_q_out[b][d][t] = sum_i w_out[d][i]*cb[idx[b*T+t]][i] + out_b[d]
__global__ __launch_bounds__(256) void out_gemm(const float* __restrict__ w,
        const float* __restrict__ cb, const ull* __restrict__ keys,
        const float* __restrict__ bias, float* __restrict__ out) {
    __shared__ float As[32 * 68];
    __shared__ float Bs[32 * 68];
    __shared__ int idxs[64];
    int b  = blockIdx.z;
    int d0 = blockIdx.y * 64;
    int t0 = blockIdx.x * 64;
    int t  = threadIdx.x;
    if (t < 64) idxs[t] = (int)(unsigned int)(keys[b * T_ + t0 + t] & 0xffffffffull);
    __syncthreads();
    int tx = t & 15, ty = t >> 4;
    float acc[4][4] = {};
    for (int kt = 0; kt < D_CB_ / 32; ++kt) {
        #pragma unroll
        for (int p = 0; p < 2; ++p) {
            int q = p * 256 + t;
            int r = q >> 3, c4 = q & 7;
            float4 x = *(const float4*)&w[(size_t)(d0 + r) * D_CB_ + kt * 32 + c4 * 4];
            As[(c4*4+0)*68 + r] = x.x; As[(c4*4+1)*68 + r] = x.y;
            As[(c4*4+2)*68 + r] = x.z; As[(c4*4+3)*68 + r] = x.w;
        }
        #pragma unroll
        for (int p = 0; p < 2; ++p) {
            int q = p * 256 + t;
            int r = q >> 3, c4 = q & 7;
            float4 x = *(const float4*)&cb[(size_t)idxs[r] * D_CB_ + kt * 32 + c4 * 4];
            Bs[(c4*4+0)*68 + r] = x.x; Bs[(c4*4+1)*68 + r] = x.y;
            Bs[(c4*4+2)*68 + r] = x.z; Bs[(c4*4+3)*68 + r] = x.w;
        }
        __syncthreads();
        #pragma unroll 4
        for (int k = 0; k < 32; ++k) {
            float a[4], bv[4];
            *(float4*)a  = *(float4*)&As[k * 68 + ty * 4];
            *(float4*)bv = *(float4*)&Bs[k * 68 + tx * 4];
            #pragma unroll
            for (int i = 0; i < 4; ++i)
                #pragma unroll
                for (int j = 0; j < 4; ++j)
                    acc[i][j] = fmaf(a[i], bv[j], acc[i][j]);
        }
        __syncthreads();
    }
    #pragma unroll
    for (int i = 0; i < 4; ++i) {
        int d = d0 + ty * 4 + i;
        float bb = bias[d];
        float4 v = make_float4(acc[i][0] + bb, acc[i][1] + bb, acc[i][2] + bb, acc[i][3] + bb);
        *(float4*)&out[(size_t)b * D_IN_ * T_ + (size_t)d * T_ + t0 + tx * 4] = v;
    }
}

// scalars: perplexity, active_num, losses
__global__ void finalize_kernel(const float* __restrict__ counts, const float* __restrict__ cs,
                                const float* __restrict__ loss, float* __restrict__ out) {
    int t = threadIdx.x;
    float H = 0.f, act = 0.f;
    for (int k = t; k < K_; k += 256) {
        float c = counts[k];
        float p = c * (1.0f / 16384.0f);
        H += p * logf(p + 1e-10f);
        float ncs = cs[k] * 0.99f + c * 0.01f;
        if (ncs > 2.0f) act += 1.0f;
    }
    __shared__ float sh[8];
    for (int o = 32; o; o >>= 1) { H += __shfl_down(H, o, 64); act += __shfl_down(act, o, 64); }
    int wave = t >> 6, lane = t & 63;
    if (lane == 0) { sh[wave] = H; sh[4 + wave] = act; }
    __syncthreads();
    if (t == 0) {
        out[OUT_PERP] = expf(-(sh[0] + sh[1] + sh[2] + sh[3]));
        out[OUT_ACT]  = sh[4] + sh[5] + sh[6] + sh[7];
    }
    if (t < 16) {
        float m = loss[t] * (1.0f / 262144.0f);
        out[OUT_COMM + t] = m * 0.15f;
        out[OUT_CB + t]   = m;
    }
}

extern "C" void kernel_launch(void* const* d_in, const int* in_sizes, int n_in,
                              void* d_out, int out_size, void* d_ws, size_t ws_size,
                              hipStream_t stream) {
    const float* z        = (const float*)d_in[0];
    const float* in_g     = (const float*)d_in[1];
    const float* in_v     = (const float*)d_in[2];
    const float* in_b     = (const float*)d_in[3];
    const float* out_g    = (const float*)d_in[4];
    const float* out_v    = (const float*)d_in[5];
    const float* out_b    = (const float*)d_in[6];
    const float* codebook = (const float*)d_in[7];
    const float* cluster  = (const float*)d_in[8];
    float* out = (float*)d_out;
    float* ws  = (float*)d_ws;
    ull* keys  = (ull*)(ws + WS_KEYS);

    float* scr = out + OUT_ZQ;
    unsigned short* ehi = (unsigned short*)(scr + SCR_EHI);
    unsigned short* elo = (unsigned short*)(scr + SCR_ELO);
    unsigned short* chi = (unsigned short*)(scr + SCR_CHI);
    unsigned short* clo = (unsigned short*)(scr + SCR_CLO);
    ull* minb  = (ull*)(scr + SCR_MINB);
    int* flags = (int*)(scr + SCR_FLAG);

    hipMemsetAsync(ws + WS_CNT, 0, (K_ + 16) * sizeof(float), stream);

    wn_kernel<<<64, 256, 0, stream>>>(in_g, in_v, ws + WS_WIN, D_CB_, D_IN_);
    wn_kernel<<<256, 256, 0, stream>>>(out_g, out_v, ws + WS_WOUT, D_IN_, D_CB_);
    split_kernel<<<K_ / 4, 256, 0, stream>>>(codebook, ws + WS_INVC, ws + WS_CSQ, chi, clo);
    ze_gemm<<<dim3(16, 4, 16), 256, 0, stream>>>(ws + WS_WIN, z, in_b, ws + WS_ENC);
    split_kernel<<<NTOK / 4, 256, 0, stream>>>(ws + WS_ENC, ws + WS_INVE, ws + WS_ESQ, ehi, elo);
    dist_mfma<<<8192, 256, 0, stream>>>(ehi, elo, chi, clo, ws + WS_ESQ, ws + WS_CSQ,
                                        out + OUT_DIST, minb);
    minreduce<<<NTOK / 4, 256, 0, stream>>>(minb, keys, flags);
    argmin_fix<<<NTOK, 64, 0, stream>>>(ws + WS_ENC, ws + WS_INVE, ws + WS_ESQ,
                                        codebook, ws + WS_INVC, ws + WS_CSQ,
                                        out + OUT_DIST, flags, keys);
    token_kernel<<<NTOK / 4, 256, 0, stream>>>(ws + WS_ENC, codebook, keys,
                                               out + OUT_IDX, ws + WS_CNT, ws + WS_LOSS);
    out_gemm<<<dim3(16, 16, 16), 256, 0, stream>>>(ws + WS_WOUT, codebook, keys,
                                                   out_b, out + OUT_ZQ);
    finalize_kernel<<<1, 256, 0, stream>>>(ws + WS_CNT, cluster, ws + WS_LOSS, out);
}

// Round 2
// 1591.844 us; speedup vs baseline: 1.1888x; 1.0148x over previous
//
#include <hip/hip_runtime.h>
#include <stdint.h>

#define B_    16
#define D_IN_ 1024
#define T_    1024
#define K_    8192
#define D_CB_ 256
#define NTOK  (B_*T_)   // 16384

typedef unsigned long long ull;
typedef __attribute__((ext_vector_type(8))) short short8;   // 8 bf16 (4 VGPRs)
typedef __attribute__((ext_vector_type(4))) float f32x4;

// ---- workspace layout (float offsets) ----
#define WS_WIN   0            // w_in  [256][1024]
#define WS_WOUT  262144       // w_out [1024][256]
#define WS_ENC   524288       // enc   [16384][256] (token-major z_e)
#define WS_INVE  4718592      // [16384]
#define WS_ESQ   4734976      // [16384]
#define WS_INVC  4751360      // [8192]
#define WS_CSQ   4759552      // [8192]
#define WS_KEYS  4767744      // u64 [16384] (argmin packed keys) = 32768 floats
#define WS_CNT   4800512      // [8192] counts (float)
#define WS_LOSS  4808704      // [16] per-batch sq-err sums
// optional extension (guarded by ws_size check at launch):
#define WS_CBH   4808720      // ushort[8192*256] raw codebook hi (1,048,576 floats)
#define WS_CBL   5857296      // ushort[8192*256] raw codebook lo
#define WS_WOH   6905872      // ushort[1024*256] w_out hi (131,072 floats)
#define WS_WOL   7036944      // ushort[1024*256] w_out lo
#define WS_EXT_END 7168016    // floats
#define WS_EXT_BYTES ((size_t)WS_EXT_END * 4)

// ---- output layout (float offsets) ----
#define OUT_ZQ   0
#define OUT_IDX  16777216
#define OUT_COMM 16793600
#define OUT_CB   16793616
#define OUT_DIST 16793632
#define OUT_PERP 151011360
#define OUT_ACT  151011361

// ---- scratch carved out of OUT_ZQ (all dead before out kernel writes OUT_ZQ) ----
#define SCR_EHI  0            // ushort[16384*256] hi bf16 of enc_n  (2,097,152 floats)
#define SCR_ELO  2097152      // ushort[16384*256] lo
#define SCR_CHI  4194304      // ushort[8192*256]  hi bf16 of cb_n   (1,048,576 floats)
#define SCR_CLO  5242880      // ushort[8192*256]  lo
#define SCR_MINB 6291456      // ull  [16384][64][2]  per (row, colblock) min1/min2
#define SCR_FLAG 10485760     // int  [16384]

#define MARGIN 2.5e-4f        // bf16x3 dist error bound ~3e-5; 8x safety

__device__ __forceinline__ float wave_sum(float s) {
    for (int o = 32; o; o >>= 1) s += __shfl_down(s, o, 64);
    return s;
}

__device__ __forceinline__ unsigned short f2bf(float f) {   // RNE fp32 -> bf16
    unsigned u = __float_as_uint(f);
    return (unsigned short)((u + 0x7fffu + ((u >> 16) & 1u)) >> 16);
}

// weight_norm dim=0: w[r][c] = g[r]*v[r][c]/||v[r]||
__global__ void wn_kernel(const float* __restrict__ g, const float* __restrict__ v,
                          float* __restrict__ w, int rows, int cols) {
    int wave = threadIdx.x >> 6, lane = threadIdx.x & 63;
    int row = blockIdx.x * 4 + wave;
    if (row >= rows) return;
    const float* vr = v + (size_t)row * cols;
    float s = 0.f;
    for (int c = lane; c < (cols >> 2); c += 64) {
        float4 x = ((const float4*)vr)[c];
        s += x.x*x.x + x.y*x.y + x.z*x.z + x.w*x.w;
    }
    s = wave_sum(s);
    s = __shfl(s, 0, 64);
    float norm = sqrtf(s);
    float gr = g[row];
    float* wr = w + (size_t)row * cols;
    for (int c = lane; c < cols; c += 64)
        wr[c] = gr * vr[c] / norm;
}

// per-row (256-col) l2 stats + bf16 hi/lo split of the normalized row
__global__ void split_kernel(const float* __restrict__ x, float* __restrict__ inv,
                             float* __restrict__ sq, unsigned short* __restrict__ hi,
                             unsigned short* __restrict__ lo) {
    int wave = threadIdx.x >> 6, lane = threadIdx.x & 63;
    int row = blockIdx.x * 4 + wave;
    float4 v = ((const float4*)(x + (size_t)row * D_CB_))[lane];
    float s = v.x*v.x + v.y*v.y + v.z*v.z + v.w*v.w;
    s = wave_sum(s);
    s = __shfl(s, 0, 64);
    float n = fmaxf(sqrtf(s), 1e-12f);
    float iv = 1.0f / n;
    if (lane == 0) { inv[row] = iv; sq[row] = s * iv * iv; }
    float f[4] = { v.x*iv, v.y*iv, v.z*iv, v.w*iv };
    unsigned short h[4], l[4];
    #pragma unroll
    for (int i = 0; i < 4; ++i) {
        h[i] = f2bf(f[i]);
        float hf = __uint_as_float((unsigned)h[i] << 16);
        l[i] = f2bf(f[i] - hf);
    }
    *(ushort4*)(hi + (size_t)row * D_CB_ + lane * 4) = make_ushort4(h[0], h[1], h[2], h[3]);
    *(ushort4*)(lo + (size_t)row * D_CB_ + lane * 4) = make_ushort4(l[0], l[1], l[2], l[3]);
}

// plain elementwise bf16 hi/lo split (no normalization)
__global__ void splitraw_kernel(const float* __restrict__ x, unsigned short* __restrict__ hi,
                                unsigned short* __restrict__ lo, int n4) {
    int i = blockIdx.x * 256 + threadIdx.x;
    if (i >= n4) return;
    float4 v = ((const float4*)x)[i];
    float f[4] = { v.x, v.y, v.z, v.w };
    unsigned short h[4], l[4];
    #pragma unroll
    for (int q = 0; q < 4; ++q) {
        h[q] = f2bf(f[q]);
        float hf = __uint_as_float((unsigned)h[q] << 16);
        l[q] = f2bf(f[q] - hf);
    }
    *(ushort4*)(hi + (size_t)i * 4) = make_ushort4(h[0], h[1], h[2], h[3]);
    *(ushort4*)(lo + (size_t)i * 4) = make_ushort4(l[0], l[1], l[2], l[3]);
}

// z_e GEMM: enc[b*T+t][o] = sum_i w_in[o][i]*z[b][i][t] + in_b[o]
// tile 64(o) x 128(t), KC=32, 256 thr, micro 4(o)x8(t).
// Per-output accumulation: single fmaf chain, k ascending -> bit-identical to reference order.
__global__ __launch_bounds__(256) void ze_gemm(const float* __restrict__ w,
        const float* __restrict__ z, const float* __restrict__ bias,
        float* __restrict__ enc) {
    __shared__ float As[32 * 68];    // A^T [k][o]
    __shared__ float Bs[32 * 132];   // B   [k][t]
    int b  = blockIdx.z;
    int o0 = blockIdx.y * 64;
    int t0 = blockIdx.x * 128;
    int t  = threadIdx.x;
    int tx = t & 15, ty = t >> 4;
    float acc[4][8] = {};            // [o_sub][t_sub]
    const float* zb = z + (size_t)b * D_IN_ * T_;
    for (int kt = 0; kt < D_IN_ / 32; ++kt) {
        #pragma unroll
        for (int p = 0; p < 2; ++p) {           // A: 64 o-rows x 32k, transpose-stage
            int q = p * 256 + t;
            int r = q >> 3, c4 = q & 7;
            float4 x = *(const float4*)&w[(size_t)(o0 + r) * D_IN_ + kt * 32 + c4 * 4];
            As[(c4*4+0)*68 + r] = x.x; As[(c4*4+1)*68 + r] = x.y;
            As[(c4*4+2)*68 + r] = x.z; As[(c4*4+3)*68 + r] = x.w;
        }
        #pragma unroll
        for (int p = 0; p < 4; ++p) {           // B: 32 k-rows x 128 t, natural
            int q = p * 256 + t;
            int r = q >> 5, c4 = q & 31;
            float4 x = *(const float4*)&zb[(size_t)(kt * 32 + r) * T_ + t0 + c4 * 4];
            *(float4*)&Bs[r * 132 + c4 * 4] = x;
        }
        __syncthreads();
        #pragma unroll 4
        for (int k = 0; k < 32; ++k) {
            float a[4], bv[8];
            *(float4*)a      = *(float4*)&As[k * 68 + ty * 4];
            *(float4*)&bv[0] = *(float4*)&Bs[k * 132 + tx * 4];
            *(float4*)&bv[4] = *(float4*)&Bs[k * 132 + 64 + tx * 4];
            #pragma unroll
            for (int i = 0; i < 4; ++i)
                #pragma unroll
                for (int j = 0; j < 8; ++j)
                    acc[i][j] = fmaf(a[i], bv[j], acc[i][j]);
        }
        __syncthreads();
    }
    float bias4[4];
    *(float4*)bias4 = *(const float4*)&bias[o0 + ty * 4];
    #pragma unroll
    for (int j = 0; j < 8; ++j) {
        int token = b * T_ + t0 + (j < 4 ? tx * 4 + j : 64 + tx * 4 + (j - 4));
        float4 v = make_float4(acc[0][j] + bias4[0], acc[1][j] + bias4[1],
                               acc[2][j] + bias4[2], acc[3][j] + bias4[3]);
        *(float4*)&enc[(size_t)token * D_CB_ + o0 + ty * 4] = v;
    }
}

// dist GEMM via bf16x3 MFMA: dist[row][col] = esq[row] + csq[col] - 2*(hh+hl+lh)
// 128x128 tile / block, 4 waves (2x2), 64x64 per wave, direct-from-L2 fragment loads.
// XCD-locality: XCD x owns 16 row-blocks (A slice ~2MB, L2-resident) and sweeps
// col-blocks slowly (each 128KB B panel reused 16x back-to-back).
__global__ __launch_bounds__(256, 3) void dist_mfma(
        const unsigned short* __restrict__ ehi, const unsigned short* __restrict__ elo,
        const unsigned short* __restrict__ chi, const unsigned short* __restrict__ clo,
        const float* __restrict__ esq, const float* __restrict__ csq,
        float* __restrict__ dist, ull* __restrict__ minb) {
    __shared__ ull pairs[2][64][2][2];
    int bid = blockIdx.x;
    int x = bid & 7;                 // XCD (block i -> XCD i%8)
    int j_ = bid >> 3;               // launch order within XCD, 0..1023
    int by = x * 16 + (j_ & 15);     // 16 row-blocks per XCD
    int bx = j_ >> 4;                // col sweep
    int r0 = by * 128, c0 = bx * 128;
    int t = threadIdx.x;
    int wave = t >> 6, lane = t & 63;
    int wm = wave >> 1, wn = wave & 1;
    int lr = lane & 15, kg = lane >> 4;

    const unsigned short* ea = ehi + (size_t)(r0 + wm*64 + lr) * D_CB_ + kg*8;
    const unsigned short* eb = elo + (size_t)(r0 + wm*64 + lr) * D_CB_ + kg*8;
    const unsigned short* ca = chi + (size_t)(c0 + wn*64 + lr) * D_CB_ + kg*8;
    const unsigned short* cl = clo + (size_t)(c0 + wn*64 + lr) * D_CB_ + kg*8;

    f32x4 acc[4][4] = {};
    for (int kt = 0; kt < D_CB_ / 32; ++kt) {
        short8 ah[4], al[4], bh[4], bl[4];
        int k = kt * 32;
        #pragma unroll
        for (int i = 0; i < 4; ++i) {
            ah[i] = *(const short8*)(ea + (size_t)i*16*D_CB_ + k);
            al[i] = *(const short8*)(eb + (size_t)i*16*D_CB_ + k);
            bh[i] = *(const short8*)(ca + (size_t)i*16*D_CB_ + k);
            bl[i] = *(const short8*)(cl + (size_t)i*16*D_CB_ + k);
        }
        #pragma unroll
        for (int i = 0; i < 4; ++i)
            #pragma unroll
            for (int j = 0; j < 4; ++j) {
                acc[i][j] = __builtin_amdgcn_mfma_f32_16x16x32_bf16(ah[i], bh[j], acc[i][j], 0, 0, 0);
                acc[i][j] = __builtin_amdgcn_mfma_f32_16x16x32_bf16(ah[i], bl[j], acc[i][j], 0, 0, 0);
                acc[i][j] = __builtin_amdgcn_mfma_f32_16x16x32_bf16(al[i], bh[j], acc[i][j], 0, 0, 0);
            }
    }
    float csqv[4];
    #pragma unroll
    for (int j = 0; j < 4; ++j) csqv[j] = csq[c0 + wn*64 + j*16 + lr];
    // D layout (m89-verified): col = lane&15, row = (lane>>4)*4 + reg
    #pragma unroll
    for (int i = 0; i < 4; ++i) {
        #pragma unroll
        for (int r = 0; r < 4; ++r) {
            int rl = i*16 + kg*4 + r;
            int grow = r0 + wm*64 + rl;
            float es = esq[grow];
            float* drow = dist + (size_t)grow * K_ + c0 + wn*64 + lr;
            ull m1 = ~0ull, m2 = ~0ull;
            #pragma unroll
            for (int j = 0; j < 4; ++j) {
                float d = fmaf(-2.0f, acc[i][j][r], es + csqv[j]);
                __builtin_nontemporal_store(d, &drow[j*16]);   // keep L2 for A/B panels
                ull key = ((ull)__float_as_uint(d) << 32) | (unsigned)(c0 + wn*64 + j*16 + lr);
                if (key < m1) { m2 = m1; m1 = key; } else if (key < m2) m2 = key;
            }
            #pragma unroll
            for (int off = 1; off < 16; off <<= 1) {   // 2-min butterfly within 16-lane col group
                ull o1 = __shfl_xor(m1, off, 64);
                ull o2 = __shfl_xor(m2, off, 64);
                ull n1 = o1 < m1 ? o1 : m1;
                ull xx = o1 < m1 ? m1 : o1;
                ull yy = o2 < m2 ? o2 : m2;
                m2 = xx < yy ? xx : yy;
                m1 = n1;
            }
            if (lr == 0) { pairs[wm][rl][wn][0] = m1; pairs[wm][rl][wn][1] = m2; }
        }
    }
    __syncthreads();
    if (t < 128) {
        int wm2 = t >> 6, rl = t & 63;
        ull a1 = pairs[wm2][rl][0][0], a2 = pairs[wm2][rl][0][1];
        ull b1 = pairs[wm2][rl][1][0], b2 = pairs[wm2][rl][1][1];
        ull m1 = a1 < b1 ? a1 : b1;
        ull xx = a1 < b1 ? b1 : a1;
        ull yy = a2 < b2 ? a2 : b2;
        ull m2 = xx < yy ? xx : yy;
        size_t grow = (size_t)(r0 + wm2*64 + rl);
        minb[(grow*64 + bx)*2 + 0] = m1;
        minb[(grow*64 + bx)*2 + 1] = m2;
    }
}

// reduce per-block min pairs -> keys[row]; flag rows whose 1st-2nd gap < MARGIN
__global__ void minreduce(const ull* __restrict__ minb, ull* __restrict__ keys,
                          int* __restrict__ flags) {
    int wave = threadIdx.x >> 6, lane = threadIdx.x & 63;
    int row = blockIdx.x * 4 + wave;
    ull m1 = minb[((size_t)row*64 + lane)*2 + 0];
    ull m2 = minb[((size_t)row*64 + lane)*2 + 1];
    #pragma unroll
    for (int off = 1; off < 64; off <<= 1) {
        ull o1 = __shfl_xor(m1, off, 64);
        ull o2 = __shfl_xor(m2, off, 64);
        ull n1 = o1 < m1 ? o1 : m1;
        ull x  = o1 < m1 ? m1 : o1;
        ull y  = o2 < m2 ? o2 : m2;
        m2 = x < y ? x : y;
        m1 = n1;
    }
    if (lane == 0) {
        keys[row] = m1;
        float d1 = __uint_as_float((unsigned)(m1 >> 32));
        float d2 = __uint_as_float((unsigned)(m2 >> 32));
        flags[row] = (d2 - d1 < MARGIN) ? 1 : 0;
    }
}

// exact fp32 argmin repair for flagged rows
__global__ void argmin_fix(const float* __restrict__ enc, const float* __restrict__ inve,
        const float* __restrict__ esq, const float* __restrict__ cb,
        const float* __restrict__ invc, const float* __restrict__ csq,
        const float* __restrict__ dist, const int* __restrict__ flags,
        ull* __restrict__ keys) {
    int row = blockIdx.x;
    if (!flags[row]) return;
    int lane = threadIdx.x;
    ull k0 = keys[row];
    float thr = __uint_as_float((unsigned)(k0 >> 32)) + MARGIN;
    float iv = inve[row];
    float4 ev = ((const float4*)(enc + (size_t)row * D_CB_))[lane];
    ev.x *= iv; ev.y *= iv; ev.z *= iv; ev.w *= iv;
    float es = esq[row];
    float best = 1e30f; int bestc = 0;
    for (int base = 0; base < K_; base += 64) {
        float d = dist[(size_t)row * K_ + base + lane];
        ull mask = __ballot(d <= thr);
        while (mask) {
            int b = __ffsll(mask) - 1;
            mask &= mask - 1;
            int c = base + b;
            float4 cv = ((const float4*)(cb + (size_t)c * D_CB_))[lane];
            float p = ev.x*cv.x + ev.y*cv.y + ev.z*cv.z + ev.w*cv.w;
            p = wave_sum(p);
            p = __shfl(p, 0, 64);
            float dx = fmaf(-2.0f * invc[c], p, es + csq[c]);
            if (dx < best) { best = dx; bestc = c; }
        }
    }
    if (lane == 0)
        keys[row] = ((ull)__float_as_uint(best) << 32) | (unsigned)bestc;
}

// per-token: indices, (z_e - z_q)^2 partial sums, histogram
__global__ void token_kernel(const float* __restrict__ enc, const float* __restrict__ cb,
        const ull* __restrict__ keys, float* __restrict__ idx_out,
        float* __restrict__ counts, float* __restrict__ loss) {
    int wave = threadIdx.x >> 6, lane = threadIdx.x & 63;
    int tok = blockIdx.x * 4 + wave;
    int idx = (int)(unsigned int)(keys[tok] & 0xffffffffull);
    float4 e = ((const float4*)(enc + (size_t)tok * D_CB_))[lane];
    float4 q = ((const float4*)(cb  + (size_t)idx * D_CB_))[lane];
    float dx = e.x - q.x, dy = e.y - q.y, dz = e.z - q.z, dw = e.w - q.w;
    float s = dx*dx + dy*dy + dz*dz + dw*dw;
    s = wave_sum(s);
    if (lane == 0) {
        idx_out[tok] = (float)idx;
        atomicAdd(&counts[idx], 1.0f);
        atomicAdd(&loss[tok >> 10], s);
    }
}

// out projection via bf16x3 MFMA: z_q_out[b][d][t] = sum_k w_out[d][k]*cb[idx[t]][k] + out_b[d]
// 128(d) x 128(t) tile, 4 waves 2x2. B operand gathered per-token from raw-cb bf16 planes.
__global__ __launch_bounds__(256, 3) void out_mfma(
        const unsigned short* __restrict__ wh, const unsigned short* __restrict__ wl,
        const unsigned short* __restrict__ cbh, const unsigned short* __restrict__ cbl,
        const ull* __restrict__ keys, const float* __restrict__ bias,
        float* __restrict__ out) {
    int b  = blockIdx.z;
    int d0 = blockIdx.y * 128;
    int t0 = blockIdx.x * 128;
    int t = threadIdx.x;
    int wave = t >> 6, lane = t & 63;
    int wm = wave >> 1, wn = wave & 1;
    int lr = lane & 15, kg = lane >> 4;

    int idx[4];
    #pragma unroll
    for (int i = 0; i < 4; ++i)
        idx[i] = (int)(unsigned)(keys[b*T_ + t0 + wn*64 + i*16 + lr] & 0xffffffffull);

    const unsigned short* wa = wh + (size_t)(d0 + wm*64 + lr) * D_CB_ + kg*8;
    const unsigned short* wb = wl + (size_t)(d0 + wm*64 + lr) * D_CB_ + kg*8;

    f32x4 acc[4][4] = {};
    for (int kt = 0; kt < D_CB_ / 32; ++kt) {
        int k = kt * 32;
        short8 ah[4], al[4], bh[4], bl[4];
        #pragma unroll
        for (int i = 0; i < 4; ++i) {
            ah[i] = *(const short8*)(wa + (size_t)i*16*D_CB_ + k);
            al[i] = *(const short8*)(wb + (size_t)i*16*D_CB_ + k);
            bh[i] = *(const short8*)(cbh + (size_t)idx[i]*D_CB_ + kg*8 + k);
            bl[i] = *(const short8*)(cbl + (size_t)idx[i]*D_CB_ + kg*8 + k);
        }
        #pragma unroll
        for (int i = 0; i < 4; ++i)
            #pragma unroll
            for (int j = 0; j < 4; ++j) {
                acc[i][j] = __builtin_amdgcn_mfma_f32_16x16x32_bf16(ah[i], bh[j], acc[i][j], 0, 0, 0);
                acc[i][j] = __builtin_amdgcn_mfma_f32_16x16x32_bf16(ah[i], bl[j], acc[i][j], 0, 0, 0);
                acc[i][j] = __builtin_amdgcn_mfma_f32_16x16x32_bf16(al[i], bh[j], acc[i][j], 0, 0, 0);
            }
    }
    float* ob = out + (size_t)b * D_IN_ * T_;
    #pragma unroll
    for (int i = 0; i < 4; ++i) {
        #pragma unroll
        for (int r = 0; r < 4; ++r) {
            int d = d0 + wm*64 + i*16 + kg*4 + r;
            float bb = bias[d];
            #pragma unroll
            for (int j = 0; j < 4; ++j) {
                int tt = t0 + wn*64 + j*16 + lr;
                __builtin_nontemporal_store(acc[i][j][r] + bb, &ob[(size_t)d * T_ + tt]);
            }
        }
    }
}

// fallback fp32 out GEMM (used when workspace too small for bf16 planes)
__global__ __launch_bounds__(256) void out_gemm(const float* __restrict__ w,
        const float* __restrict__ cb, const ull* __restrict__ keys,
        const float* __restrict__ bias, float* __restrict__ out) {
    __shared__ float As[32 * 68];
    __shared__ float Bs[32 * 68];
    __shared__ int idxs[64];
    int b  = blockIdx.z;
    int d0 = blockIdx.y * 64;
    int t0 = blockIdx.x * 64;
    int t  = threadIdx.x;
    if (t < 64) idxs[t] = (int)(unsigned int)(keys[b * T_ + t0 + t] & 0xffffffffull);
    __syncthreads();
    int tx = t & 15, ty = t >> 4;
    float acc[4][4] = {};
    for (int kt = 0; kt < D_CB_ / 32; ++kt) {
        #pragma unroll
        for (int p = 0; p < 2; ++p) {
            int q = p * 256 + t;
            int r = q >> 3, c4 = q & 7;
            float4 x = *(const float4*)&w[(size_t)(d0 + r) * D_CB_ + kt * 32 + c4 * 4];
            As[(c4*4+0)*68 + r] = x.x; As[(c4*4+1)*68 + r] = x.y;
            As[(c4*4+2)*68 + r] = x.z; As[(c4*4+3)*68 + r] = x.w;
        }
        #pragma unroll
        for (int p = 0; p < 2; ++p) {
            int q = p * 256 + t;
            int r = q >> 3, c4 = q & 7;
            float4 x = *(const float4*)&cb[(size_t)idxs[r] * D_CB_ + kt * 32 + c4 * 4];
            Bs[(c4*4+0)*68 + r] = x.x; Bs[(c4*4+1)*68 + r] = x.y;
            Bs[(c4*4+2)*68 + r] = x.z; Bs[(c4*4+3)*68 + r] = x.w;
        }
        __syncthreads();
        #pragma unroll 4
        for (int k = 0; k < 32; ++k) {
            float a[4], bv[4];
            *(float4*)a  = *(float4*)&As[k * 68 + ty * 4];
            *(float4*)bv = *(float4*)&Bs[k * 68 + tx * 4];
            #pragma unroll
            for (int i = 0; i < 4; ++i)
                #pragma unroll
                for (int j = 0; j < 4; ++j)
                    acc[i][j] = fmaf(a[i], bv[j], acc[i][j]);
        }
        __syncthreads();
    }
    #pragma unroll
    for (int i = 0; i < 4; ++i) {
        int d = d0 + ty * 4 + i;
        float bb = bias[d];
        float4 v = make_float4(acc[i][0] + bb, acc[i][1] + bb, acc[i][2] + bb, acc[i][3] + bb);
        *(float4*)&out[(size_t)b * D_IN_ * T_ + (size_t)d * T_ + t0 + tx * 4] = v;
    }
}

// scalars: perplexity, active_num, losses
__global__ void finalize_kernel(const float* __restrict__ counts, const float* __restrict__ cs,
                                const float* __restrict__ loss, float* __restrict__ out) {
    int t = threadIdx.x;
    float H = 0.f, act = 0.f;
    for (int k = t; k < K_; k += 256) {
        float c = counts[k];
        float p = c * (1.0f / 16384.0f);
        H += p * logf(p + 1e-10f);
        float ncs = cs[k] * 0.99f + c * 0.01f;
        if (ncs > 2.0f) act += 1.0f;
    }
    __shared__ float sh[8];
    for (int o = 32; o; o >>= 1) { H += __shfl_down(H, o, 64); act += __shfl_down(act, o, 64); }
    int wave = t >> 6, lane = t & 63;
    if (lane == 0) { sh[wave] = H; sh[4 + wave] = act; }
    __syncthreads();
    if (t == 0) {
        out[OUT_PERP] = expf(-(sh[0] + sh[1] + sh[2] + sh[3]));
        out[OUT_ACT]  = sh[4] + sh[5] + sh[6] + sh[7];
    }
    if (t < 16) {
        float m = loss[t] * (1.0f / 262144.0f);
        out[OUT_COMM + t] = m * 0.15f;
        out[OUT_CB + t]   = m;
    }
}

extern "C" void kernel_launch(void* const* d_in, const int* in_sizes, int n_in,
                              void* d_out, int out_size, void* d_ws, size_t ws_size,
                              hipStream_t stream) {
    const float* z        = (const float*)d_in[0];
    const float* in_g     = (const float*)d_in[1];
    const float* in_v     = (const float*)d_in[2];
    const float* in_b     = (const float*)d_in[3];
    const float* out_g    = (const float*)d_in[4];
    const float* out_v    = (const float*)d_in[5];
    const float* out_b    = (const float*)d_in[6];
    const float* codebook = (const float*)d_in[7];
    const float* cluster  = (const float*)d_in[8];
    float* out = (float*)d_out;
    float* ws  = (float*)d_ws;
    ull* keys  = (ull*)(ws + WS_KEYS);

    float* scr = out + OUT_ZQ;
    unsigned short* ehi = (unsigned short*)(scr + SCR_EHI);
    unsigned short* elo = (unsigned short*)(scr + SCR_ELO);
    unsigned short* chi = (unsigned short*)(scr + SCR_CHI);
    unsigned short* clo = (unsigned short*)(scr + SCR_CLO);
    ull* minb  = (ull*)(scr + SCR_MINB);
    int* flags = (int*)(scr + SCR_FLAG);

    bool mfma_out = ws_size >= WS_EXT_BYTES;   // bf16 planes must NOT live in OUT_ZQ (race)

    hipMemsetAsync(ws + WS_CNT, 0, (K_ + 16) * sizeof(float), stream);

    wn_kernel<<<64, 256, 0, stream>>>(in_g, in_v, ws + WS_WIN, D_CB_, D_IN_);
    wn_kernel<<<256, 256, 0, stream>>>(out_g, out_v, ws + WS_WOUT, D_IN_, D_CB_);
    split_kernel<<<K_ / 4, 256, 0, stream>>>(codebook, ws + WS_INVC, ws + WS_CSQ, chi, clo);
    if (mfma_out) {
        splitraw_kernel<<<2048, 256, 0, stream>>>(codebook,
                (unsigned short*)(ws + WS_CBH), (unsigned short*)(ws + WS_CBL), K_ * D_CB_ / 4);
        splitraw_kernel<<<256, 256, 0, stream>>>(ws + WS_WOUT,
                (unsigned short*)(ws + WS_WOH), (unsigned short*)(ws + WS_WOL), D_IN_ * D_CB_ / 4);
    }
    ze_gemm<<<dim3(8, 4, 16), 256, 0, stream>>>(ws + WS_WIN, z, in_b, ws + WS_ENC);
    split_kernel<<<NTOK / 4, 256, 0, stream>>>(ws + WS_ENC, ws + WS_INVE, ws + WS_ESQ, ehi, elo);
    dist_mfma<<<8192, 256, 0, stream>>>(ehi, elo, chi, clo, ws + WS_ESQ, ws + WS_CSQ,
                                        out + OUT_DIST, minb);
    minreduce<<<NTOK / 4, 256, 0, stream>>>(minb, keys, flags);
    argmin_fix<<<NTOK, 64, 0, stream>>>(ws + WS_ENC, ws + WS_INVE, ws + WS_ESQ,
                                        codebook, ws + WS_INVC, ws + WS_CSQ,
                                        out + OUT_DIST, flags, keys);
    token_kernel<<<NTOK / 4, 256, 0, stream>>>(ws + WS_ENC, codebook, keys,
                                               out + OUT_IDX, ws + WS_CNT, ws + WS_LOSS);
    if (mfma_out) {
        out_mfma<<<dim3(8, 8, 16), 256, 0, stream>>>(
                (const unsigned short*)(ws + WS_WOH), (const unsigned short*)(ws + WS_WOL),
                (const unsigned short*)(ws + WS_CBH), (const unsigned short*)(ws + WS_CBL),
                keys, out_b, out + OUT_ZQ);
    } else {
        out_gemm<<<dim3(16, 16, 16), 256, 0, stream>>>(ws + WS_WOUT, codebook, keys,
                                                       out_b, out + OUT_ZQ);
    }
    finalize_kernel<<<1, 256, 0, stream>>>(ws + WS_CNT, cluster, ws + WS_LOSS, out);
}

// Round 3
// 1580.373 us; speedup vs baseline: 1.1974x; 1.0073x over previous
//
#include <hip/hip_runtime.h>
#include <stdint.h>

#define B_    16
#define D_IN_ 1024
#define T_    1024
#define K_    8192
#define D_CB_ 256
#define NTOK  (B_*T_)   // 16384

typedef unsigned long long ull;
typedef __attribute__((ext_vector_type(8))) short short8;   // 8 bf16 (4 VGPRs)
typedef __attribute__((ext_vector_type(4))) float f32x4;

// ---- workspace layout (float offsets) ----
#define WS_WIN   0            // w_in  [256][1024]; later: w_out bf16 hi/lo planes
#define WS_WOUT  262144       // w_out [1024][256]
#define WS_ENC   524288       // enc   [16384][256]; later: z_q bf16 hi/lo planes
#define WS_INVE  4718592      // [16384]
#define WS_ESQ   4734976      // [16384]
#define WS_INVC  4751360      // [8192]
#define WS_CSQ   4759552      // [8192]
#define WS_KEYS  4767744      // u64 [16384] (argmin packed keys)
#define WS_CNT   4800512      // [8192] counts (float)
#define WS_LOSS  4808704      // [16] per-batch sq-err sums

// ---- output layout (float offsets) ----
#define OUT_ZQ   0
#define OUT_IDX  16777216
#define OUT_COMM 16793600
#define OUT_CB   16793616
#define OUT_DIST 16793632
#define OUT_PERP 151011360
#define OUT_ACT  151011361

// ---- scratch carved out of OUT_ZQ (all dead before out_mfma writes OUT_ZQ) ----
#define SCR_EHI  0            // ushort[16384*256] hi bf16 of enc_n
#define SCR_ELO  2097152      // ushort[16384*256] lo
#define SCR_CHI  4194304      // ushort[8192*256]  hi bf16 of cb_n
#define SCR_CLO  5242880      // ushort[8192*256]  lo
#define SCR_MINB 6291456      // ull  [16384][64][2]  per (row, colblock) min1/min2
#define SCR_FLAG 10485760     // int  [16384]

#define MARGIN 2.5e-4f        // bf16x3 dist error bound ~3e-5; 8x safety

__device__ __forceinline__ float wave_sum(float s) {
    for (int o = 32; o; o >>= 1) s += __shfl_down(s, o, 64);
    return s;
}

__device__ __forceinline__ unsigned short f2bf(float f) {   // RNE fp32 -> bf16
    unsigned u = __float_as_uint(f);
    return (unsigned short)((u + 0x7fffu + ((u >> 16) & 1u)) >> 16);
}

// order-preserving float->uint (handles negatives)
__device__ __forceinline__ unsigned fkey(float f) {
    unsigned u = __float_as_uint(f);
    return u ^ (unsigned)(((int)u >> 31) | 0x80000000);
}
__device__ __forceinline__ float fdec(unsigned k) {
    unsigned u = (k & 0x80000000u) ? (k ^ 0x80000000u) : ~k;
    return __uint_as_float(u);
}

// merge two (min1,min2) pairs
__device__ __forceinline__ void merge2(ull& m1, ull& m2, ull o1, ull o2) {
    ull n1 = o1 < m1 ? o1 : m1;
    ull hi = o1 < m1 ? m1 : o1;
    ull lo = o2 < m2 ? o2 : m2;
    m2 = hi < lo ? hi : lo;
    m1 = n1;
}

// weight_norm dim=0: w[r][c] = g[r]*v[r][c]/||v[r]||
__global__ void wn_kernel(const float* __restrict__ g, const float* __restrict__ v,
                          float* __restrict__ w, int rows, int cols) {
    int wave = threadIdx.x >> 6, lane = threadIdx.x & 63;
    int row = blockIdx.x * 4 + wave;
    if (row >= rows) return;
    const float* vr = v + (size_t)row * cols;
    float s = 0.f;
    for (int c = lane; c < (cols >> 2); c += 64) {
        float4 x = ((const float4*)vr)[c];
        s += x.x*x.x + x.y*x.y + x.z*x.z + x.w*x.w;
    }
    s = wave_sum(s);
    s = __shfl(s, 0, 64);
    float norm = sqrtf(s);
    float gr = g[row];
    float* wr = w + (size_t)row * cols;
    for (int c = lane; c < cols; c += 64)
        wr[c] = gr * vr[c] / norm;
}

// per-row (256-col) l2 stats + bf16 hi/lo split of the normalized row
__global__ void split_kernel(const float* __restrict__ x, float* __restrict__ inv,
                             float* __restrict__ sq, unsigned short* __restrict__ hi,
                             unsigned short* __restrict__ lo) {
    int wave = threadIdx.x >> 6, lane = threadIdx.x & 63;
    int row = blockIdx.x * 4 + wave;
    float4 v = ((const float4*)(x + (size_t)row * D_CB_))[lane];
    float s = v.x*v.x + v.y*v.y + v.z*v.z + v.w*v.w;
    s = wave_sum(s);
    s = __shfl(s, 0, 64);
    float n = fmaxf(sqrtf(s), 1e-12f);
    float iv = 1.0f / n;
    if (lane == 0) { inv[row] = iv; sq[row] = s * iv * iv; }
    float f[4] = { v.x*iv, v.y*iv, v.z*iv, v.w*iv };
    unsigned short h[4], l[4];
    #pragma unroll
    for (int i = 0; i < 4; ++i) {
        h[i] = f2bf(f[i]);
        float hf = __uint_as_float((unsigned)h[i] << 16);
        l[i] = f2bf(f[i] - hf);
    }
    *(ushort4*)(hi + (size_t)row * D_CB_ + lane * 4) = make_ushort4(h[0], h[1], h[2], h[3]);
    *(ushort4*)(lo + (size_t)row * D_CB_ + lane * 4) = make_ushort4(l[0], l[1], l[2], l[3]);
}

// plain elementwise bf16 hi/lo split (no normalization)
__global__ void splitraw_kernel(const float* __restrict__ x, unsigned short* __restrict__ hi,
                                unsigned short* __restrict__ lo, int n4) {
    int i = blockIdx.x * 256 + threadIdx.x;
    if (i >= n4) return;
    float4 v = ((const float4*)x)[i];
    float f[4] = { v.x, v.y, v.z, v.w };
    unsigned short h[4], l[4];
    #pragma unroll
    for (int q = 0; q < 4; ++q) {
        h[q] = f2bf(f[q]);
        float hf = __uint_as_float((unsigned)h[q] << 16);
        l[q] = f2bf(f[q] - hf);
    }
    *(ushort4*)(hi + (size_t)i * 4) = make_ushort4(h[0], h[1], h[2], h[3]);
    *(ushort4*)(lo + (size_t)i * 4) = make_ushort4(l[0], l[1], l[2], l[3]);
}

// per-token gather: z_q bf16 hi/lo planes (dense, token-major) from codebook rows
__global__ void zq_split(const float* __restrict__ cb, const ull* __restrict__ keys,
                         unsigned short* __restrict__ qh, unsigned short* __restrict__ ql) {
    int wave = threadIdx.x >> 6, lane = threadIdx.x & 63;
    int tok = blockIdx.x * 4 + wave;
    int idx = (int)(unsigned)(keys[tok] & 0xffffffffull);
    float4 v = ((const float4*)(cb + (size_t)idx * D_CB_))[lane];
    float f[4] = { v.x, v.y, v.z, v.w };
    unsigned short h[4], l[4];
    #pragma unroll
    for (int q = 0; q < 4; ++q) {
        h[q] = f2bf(f[q]);
        float hf = __uint_as_float((unsigned)h[q] << 16);
        l[q] = f2bf(f[q] - hf);
    }
    *(ushort4*)(qh + (size_t)tok * D_CB_ + lane * 4) = make_ushort4(h[0], h[1], h[2], h[3]);
    *(ushort4*)(ql + (size_t)tok * D_CB_ + lane * 4) = make_ushort4(l[0], l[1], l[2], l[3]);
}

// z_e GEMM: enc[b*T+t][o] = sum_i w_in[o][i]*z[b][i][t] + in_b[o]
// tile 64(o) x 128(t), KC=32, 256 thr, micro 4(o)x8(t).
__global__ __launch_bounds__(256) void ze_gemm(const float* __restrict__ w,
        const float* __restrict__ z, const float* __restrict__ bias,
        float* __restrict__ enc) {
    __shared__ float As[32 * 68];    // A^T [k][o]
    __shared__ float Bs[32 * 132];   // B   [k][t]
    int b  = blockIdx.z;
    int o0 = blockIdx.y * 64;
    int t0 = blockIdx.x * 128;
    int t  = threadIdx.x;
    int tx = t & 15, ty = t >> 4;
    float acc[4][8] = {};            // [o_sub][t_sub]
    const float* zb = z + (size_t)b * D_IN_ * T_;
    for (int kt = 0; kt < D_IN_ / 32; ++kt) {
        #pragma unroll
        for (int p = 0; p < 2; ++p) {           // A: 64 o-rows x 32k, transpose-stage
            int q = p * 256 + t;
            int r = q >> 3, c4 = q & 7;
            float4 x = *(const float4*)&w[(size_t)(o0 + r) * D_IN_ + kt * 32 + c4 * 4];
            As[(c4*4+0)*68 + r] = x.x; As[(c4*4+1)*68 + r] = x.y;
            As[(c4*4+2)*68 + r] = x.z; As[(c4*4+3)*68 + r] = x.w;
        }
        #pragma unroll
        for (int p = 0; p < 4; ++p) {           // B: 32 k-rows x 128 t, natural
            int q = p * 256 + t;
            int r = q >> 5, c4 = q & 31;
            float4 x = *(const float4*)&zb[(size_t)(kt * 32 + r) * T_ + t0 + c4 * 4];
            *(float4*)&Bs[r * 132 + c4 * 4] = x;
        }
        __syncthreads();
        #pragma unroll 4
        for (int k = 0; k < 32; ++k) {
            float a[4], bv[8];
            *(float4*)a      = *(float4*)&As[k * 68 + ty * 4];
            *(float4*)&bv[0] = *(float4*)&Bs[k * 132 + tx * 4];
            *(float4*)&bv[4] = *(float4*)&Bs[k * 132 + 64 + tx * 4];
            #pragma unroll
            for (int i = 0; i < 4; ++i)
                #pragma unroll
                for (int j = 0; j < 8; ++j)
                    acc[i][j] = fmaf(a[i], bv[j], acc[i][j]);
        }
        __syncthreads();
    }
    float bias4[4];
    *(float4*)bias4 = *(const float4*)&bias[o0 + ty * 4];
    #pragma unroll
    for (int j = 0; j < 8; ++j) {
        int token = b * T_ + t0 + (j < 4 ? tx * 4 + j : 64 + tx * 4 + (j - 4));
        float4 v = make_float4(acc[0][j] + bias4[0], acc[1][j] + bias4[1],
                               acc[2][j] + bias4[2], acc[3][j] + bias4[3]);
        *(float4*)&enc[(size_t)token * D_CB_ + o0 + ty * 4] = v;
    }
}

// dist GEMM via bf16x3 MFMA. 128x128 tile, 4 waves (2x2), 64x64 per wave.
// XCD-locality: XCD x owns 16 row-blocks (A slice L2-resident), sweeps cols slowly.
// Argmin: per-lane 4-way j-min -> 2 butterfly rounds (lr 16->4) -> LDS pairs ->
// single 128-thread merge pass (replaces the 5-round-per-(i,r) butterfly epilogue).
__global__ __launch_bounds__(256) void dist_mfma(
        const unsigned short* __restrict__ ehi, const unsigned short* __restrict__ elo,
        const unsigned short* __restrict__ chi, const unsigned short* __restrict__ clo,
        const float* __restrict__ esq, const float* __restrict__ csq,
        float* __restrict__ dist, ull* __restrict__ minb) {
    __shared__ ull pairs[2][64][2][4][2];   // [wm][rl][wn][lr>>2][m1/m2] = 16 KB
    int bid = blockIdx.x;
    int x = bid & 7;                 // XCD
    int j_ = bid >> 3;
    int by = x * 16 + (j_ & 15);     // 16 row-blocks per XCD
    int bx = j_ >> 4;                // col sweep
    int r0 = by * 128, c0 = bx * 128;
    int t = threadIdx.x;
    int wave = t >> 6, lane = t & 63;
    int wm = wave >> 1, wn = wave & 1;
    int lr = lane & 15, kg = lane >> 4;

    const unsigned short* ea = ehi + (size_t)(r0 + wm*64 + lr) * D_CB_ + kg*8;
    const unsigned short* eb = elo + (size_t)(r0 + wm*64 + lr) * D_CB_ + kg*8;
    const unsigned short* ca = chi + (size_t)(c0 + wn*64 + lr) * D_CB_ + kg*8;
    const unsigned short* cl = clo + (size_t)(c0 + wn*64 + lr) * D_CB_ + kg*8;

    f32x4 acc[4][4] = {};
    for (int kt = 0; kt < D_CB_ / 32; ++kt) {
        short8 ah[4], al[4], bh[4], bl[4];
        int k = kt * 32;
        #pragma unroll
        for (int i = 0; i < 4; ++i) {
            ah[i] = *(const short8*)(ea + (size_t)i*16*D_CB_ + k);
            al[i] = *(const short8*)(eb + (size_t)i*16*D_CB_ + k);
            bh[i] = *(const short8*)(ca + (size_t)i*16*D_CB_ + k);
            bl[i] = *(const short8*)(cl + (size_t)i*16*D_CB_ + k);
        }
        #pragma unroll
        for (int i = 0; i < 4; ++i)
            #pragma unroll
            for (int j = 0; j < 4; ++j) {
                acc[i][j] = __builtin_amdgcn_mfma_f32_16x16x32_bf16(ah[i], bh[j], acc[i][j], 0, 0, 0);
                acc[i][j] = __builtin_amdgcn_mfma_f32_16x16x32_bf16(ah[i], bl[j], acc[i][j], 0, 0, 0);
                acc[i][j] = __builtin_amdgcn_mfma_f32_16x16x32_bf16(al[i], bh[j], acc[i][j], 0, 0, 0);
            }
    }
    float csqv[4];
    #pragma unroll
    for (int j = 0; j < 4; ++j) csqv[j] = csq[c0 + wn*64 + j*16 + lr];
    // D layout (m89-verified): col = lane&15, row = (lane>>4)*4 + reg
    #pragma unroll
    for (int i = 0; i < 4; ++i) {
        #pragma unroll
        for (int r = 0; r < 4; ++r) {
            int rl = i*16 + kg*4 + r;
            int grow = r0 + wm*64 + rl;
            float es = esq[grow];
            float* drow = dist + (size_t)grow * K_ + c0 + wn*64 + lr;
            ull m1 = ~0ull, m2 = ~0ull;
            #pragma unroll
            for (int j = 0; j < 4; ++j) {
                float d = fmaf(-2.0f, acc[i][j][r], es + csqv[j]);
                __builtin_nontemporal_store(d, &drow[j*16]);
                ull key = ((ull)fkey(d) << 32) | (unsigned)(c0 + wn*64 + j*16 + lr);
                if (key < m1) { m2 = m1; m1 = key; } else if (key < m2) m2 = key;
            }
            #pragma unroll
            for (int off = 1; off <= 2; off <<= 1) {   // lr 16 -> 4 survivors
                ull o1 = __shfl_xor(m1, off, 64);
                ull o2 = __shfl_xor(m2, off, 64);
                merge2(m1, m2, o1, o2);
            }
            if ((lr & 3) == 0) {
                pairs[wm][rl][wn][lr >> 2][0] = m1;
                pairs[wm][rl][wn][lr >> 2][1] = m2;
            }
        }
    }
    __syncthreads();
    if (t < 128) {
        int wm2 = t >> 6, rl = t & 63;
        ull m1 = ~0ull, m2 = ~0ull;
        #pragma unroll
        for (int wn2 = 0; wn2 < 2; ++wn2)
            #pragma unroll
            for (int s = 0; s < 4; ++s)
                merge2(m1, m2, pairs[wm2][rl][wn2][s][0], pairs[wm2][rl][wn2][s][1]);
        size_t grow = (size_t)(r0 + wm2*64 + rl);
        minb[(grow*64 + bx)*2 + 0] = m1;
        minb[(grow*64 + bx)*2 + 1] = m2;
    }
}

// reduce per-block min pairs -> keys[row]; flag rows whose 1st-2nd gap < MARGIN
__global__ void minreduce(const ull* __restrict__ minb, ull* __restrict__ keys,
                          int* __restrict__ flags) {
    int wave = threadIdx.x >> 6, lane = threadIdx.x & 63;
    int row = blockIdx.x * 4 + wave;
    ull m1 = minb[((size_t)row*64 + lane)*2 + 0];
    ull m2 = minb[((size_t)row*64 + lane)*2 + 1];
    #pragma unroll
    for (int off = 1; off < 64; off <<= 1) {
        ull o1 = __shfl_xor(m1, off, 64);
        ull o2 = __shfl_xor(m2, off, 64);
        merge2(m1, m2, o1, o2);
    }
    if (lane == 0) {
        keys[row] = m1;
        float d1 = fdec((unsigned)(m1 >> 32));
        float d2 = fdec((unsigned)(m2 >> 32));
        flags[row] = (d2 - d1 < MARGIN) ? 1 : 0;
    }
}

// exact fp32 argmin repair for flagged rows
__global__ void argmin_fix(const float* __restrict__ enc, const float* __restrict__ inve,
        const float* __restrict__ esq, const float* __restrict__ cb,
        const float* __restrict__ invc, const float* __restrict__ csq,
        const float* __restrict__ dist, const int* __restrict__ flags,
        ull* __restrict__ keys) {
    int row = blockIdx.x;
    if (!flags[row]) return;
    int lane = threadIdx.x;
    ull k0 = keys[row];
    float thr = fdec((unsigned)(k0 >> 32)) + MARGIN;
    float iv = inve[row];
    float4 ev = ((const float4*)(enc + (size_t)row * D_CB_))[lane];
    ev.x *= iv; ev.y *= iv; ev.z *= iv; ev.w *= iv;
    float es = esq[row];
    float best = 1e30f; int bestc = 0;
    for (int base = 0; base < K_; base += 64) {
        float d = dist[(size_t)row * K_ + base + lane];
        ull mask = __ballot(d <= thr);
        while (mask) {
            int b = __ffsll(mask) - 1;
            mask &= mask - 1;
            int c = base + b;
            float4 cv = ((const float4*)(cb + (size_t)c * D_CB_))[lane];
            float p = ev.x*cv.x + ev.y*cv.y + ev.z*cv.z + ev.w*cv.w;
            p = wave_sum(p);
            p = __shfl(p, 0, 64);
            float dx = fmaf(-2.0f * invc[c], p, es + csq[c]);
            if (dx < best) { best = dx; bestc = c; }
        }
    }
    if (lane == 0)
        keys[row] = ((ull)fkey(best) << 32) | (unsigned)bestc;
}

// per-token: indices, (z_e - z_q)^2 partial sums, histogram
__global__ void token_kernel(const float* __restrict__ enc, const float* __restrict__ cb,
        const ull* __restrict__ keys, float* __restrict__ idx_out,
        float* __restrict__ counts, float* __restrict__ loss) {
    int wave = threadIdx.x >> 6, lane = threadIdx.x & 63;
    int tok = blockIdx.x * 4 + wave;
    int idx = (int)(unsigned int)(keys[tok] & 0xffffffffull);
    float4 e = ((const float4*)(enc + (size_t)tok * D_CB_))[lane];
    float4 q = ((const float4*)(cb  + (size_t)idx * D_CB_))[lane];
    float dx = e.x - q.x, dy = e.y - q.y, dz = e.z - q.z, dw = e.w - q.w;
    float s = dx*dx + dy*dy + dz*dz + dw*dw;
    s = wave_sum(s);
    if (lane == 0) {
        idx_out[tok] = (float)idx;
        atomicAdd(&counts[idx], 1.0f);
        atomicAdd(&loss[tok >> 10], s);
    }
}

// out projection via bf16x3 MFMA, dense operands (pre-gathered z_q planes):
// z_q_out[b][d][t] = sum_k w_out[d][k]*zq[tok][k] + out_b[d]
__global__ __launch_bounds__(256) void out_mfma(
        const unsigned short* __restrict__ wh, const unsigned short* __restrict__ wl,
        const unsigned short* __restrict__ qh, const unsigned short* __restrict__ ql,
        const float* __restrict__ bias, float* __restrict__ out) {
    int d0  = blockIdx.y * 128;
    int tk0 = blockIdx.x * 128;          // token tile (128 | 1024 -> single batch)
    int b   = tk0 >> 10;
    int t0  = tk0 & 1023;
    int t = threadIdx.x;
    int wave = t >> 6, lane = t & 63;
    int wm = wave >> 1, wn = wave & 1;
    int lr = lane & 15, kg = lane >> 4;

    const unsigned short* wa = wh + (size_t)(d0 + wm*64 + lr) * D_CB_ + kg*8;
    const unsigned short* wb = wl + (size_t)(d0 + wm*64 + lr) * D_CB_ + kg*8;
    const unsigned short* qa = qh + (size_t)(tk0 + wn*64 + lr) * D_CB_ + kg*8;
    const unsigned short* qb = ql + (size_t)(tk0 + wn*64 + lr) * D_CB_ + kg*8;

    f32x4 acc[4][4] = {};
    for (int kt = 0; kt < D_CB_ / 32; ++kt) {
        int k = kt * 32;
        short8 ah[4], al[4], bh[4], bl[4];
        #pragma unroll
        for (int i = 0; i < 4; ++i) {
            ah[i] = *(const short8*)(wa + (size_t)i*16*D_CB_ + k);
            al[i] = *(const short8*)(wb + (size_t)i*16*D_CB_ + k);
            bh[i] = *(const short8*)(qa + (size_t)i*16*D_CB_ + k);
            bl[i] = *(const short8*)(qb + (size_t)i*16*D_CB_ + k);
        }
        #pragma unroll
        for (int i = 0; i < 4; ++i)
            #pragma unroll
            for (int j = 0; j < 4; ++j) {
                acc[i][j] = __builtin_amdgcn_mfma_f32_16x16x32_bf16(ah[i], bh[j], acc[i][j], 0, 0, 0);
                acc[i][j] = __builtin_amdgcn_mfma_f32_16x16x32_bf16(ah[i], bl[j], acc[i][j], 0, 0, 0);
                acc[i][j] = __builtin_amdgcn_mfma_f32_16x16x32_bf16(al[i], bh[j], acc[i][j], 0, 0, 0);
            }
    }
    float* ob = out + (size_t)b * D_IN_ * T_;
    #pragma unroll
    for (int i = 0; i < 4; ++i) {
        #pragma unroll
        for (int r = 0; r < 4; ++r) {
            int d = d0 + wm*64 + i*16 + kg*4 + r;
            float bb = bias[d];
            #pragma unroll
            for (int j = 0; j < 4; ++j) {
                int tt = t0 + wn*64 + j*16 + lr;
                __builtin_nontemporal_store(acc[i][j][r] + bb, &ob[(size_t)d * T_ + tt]);
            }
        }
    }
}

// scalars: perplexity, active_num, losses
__global__ void finalize_kernel(const float* __restrict__ counts, const float* __restrict__ cs,
                                const float* __restrict__ loss, float* __restrict__ out) {
    int t = threadIdx.x;
    float H = 0.f, act = 0.f;
    for (int k = t; k < K_; k += 256) {
        float c = counts[k];
        float p = c * (1.0f / 16384.0f);
        H += p * logf(p + 1e-10f);
        float ncs = cs[k] * 0.99f + c * 0.01f;
        if (ncs > 2.0f) act += 1.0f;
    }
    __shared__ float sh[8];
    for (int o = 32; o; o >>= 1) { H += __shfl_down(H, o, 64); act += __shfl_down(act, o, 64); }
    int wave = t >> 6, lane = t & 63;
    if (lane == 0) { sh[wave] = H; sh[4 + wave] = act; }
    __syncthreads();
    if (t == 0) {
        out[OUT_PERP] = expf(-(sh[0] + sh[1] + sh[2] + sh[3]));
        out[OUT_ACT]  = sh[4] + sh[5] + sh[6] + sh[7];
    }
    if (t < 16) {
        float m = loss[t] * (1.0f / 262144.0f);
        out[OUT_COMM + t] = m * 0.15f;
        out[OUT_CB + t]   = m;
    }
}

extern "C" void kernel_launch(void* const* d_in, const int* in_sizes, int n_in,
                              void* d_out, int out_size, void* d_ws, size_t ws_size,
                              hipStream_t stream) {
    const float* z        = (const float*)d_in[0];
    const float* in_g     = (const float*)d_in[1];
    const float* in_v     = (const float*)d_in[2];
    const float* in_b     = (const float*)d_in[3];
    const float* out_g    = (const float*)d_in[4];
    const float* out_v    = (const float*)d_in[5];
    const float* out_b    = (const float*)d_in[6];
    const float* codebook = (const float*)d_in[7];
    const float* cluster  = (const float*)d_in[8];
    float* out = (float*)d_out;
    float* ws  = (float*)d_ws;
    ull* keys  = (ull*)(ws + WS_KEYS);

    float* scr = out + OUT_ZQ;
    unsigned short* ehi = (unsigned short*)(scr + SCR_EHI);
    unsigned short* elo = (unsigned short*)(scr + SCR_ELO);
    unsigned short* chi = (unsigned short*)(scr + SCR_CHI);
    unsigned short* clo = (unsigned short*)(scr + SCR_CLO);
    ull* minb  = (ull*)(scr + SCR_MINB);
    int* flags = (int*)(scr + SCR_FLAG);

    // dead-region reuse: WS_ENC (after token_kernel) holds z_q bf16 planes;
    // WS_WIN (after ze_gemm) holds w_out bf16 planes.
    unsigned short* zqh = (unsigned short*)(ws + WS_ENC);
    unsigned short* zql = (unsigned short*)(ws + WS_ENC + 2097152);
    unsigned short* woh = (unsigned short*)(ws + WS_WIN);
    unsigned short* wol = (unsigned short*)(ws + WS_WIN + 131072);

    hipMemsetAsync(ws + WS_CNT, 0, (K_ + 16) * sizeof(float), stream);

    wn_kernel<<<64, 256, 0, stream>>>(in_g, in_v, ws + WS_WIN, D_CB_, D_IN_);
    wn_kernel<<<256, 256, 0, stream>>>(out_g, out_v, ws + WS_WOUT, D_IN_, D_CB_);
    split_kernel<<<K_ / 4, 256, 0, stream>>>(codebook, ws + WS_INVC, ws + WS_CSQ, chi, clo);
    ze_gemm<<<dim3(8, 4, 16), 256, 0, stream>>>(ws + WS_WIN, z, in_b, ws + WS_ENC);
    split_kernel<<<NTOK / 4, 256, 0, stream>>>(ws + WS_ENC, ws + WS_INVE, ws + WS_ESQ, ehi, elo);
    dist_mfma<<<8192, 256, 0, stream>>>(ehi, elo, chi, clo, ws + WS_ESQ, ws + WS_CSQ,
                                        out + OUT_DIST, minb);
    minreduce<<<NTOK / 4, 256, 0, stream>>>(minb, keys, flags);
    argmin_fix<<<NTOK, 64, 0, stream>>>(ws + WS_ENC, ws + WS_INVE, ws + WS_ESQ,
                                        codebook, ws + WS_INVC, ws + WS_CSQ,
                                        out + OUT_DIST, flags, keys);
    token_kernel<<<NTOK / 4, 256, 0, stream>>>(ws + WS_ENC, codebook, keys,
                                               out + OUT_IDX, ws + WS_CNT, ws + WS_LOSS);
    // enc now dead -> build dense bf16 operands for the out projection
    splitraw_kernel<<<256, 256, 0, stream>>>(ws + WS_WOUT, woh, wol, D_IN_ * D_CB_ / 4);
    zq_split<<<NTOK / 4, 256, 0, stream>>>(codebook, keys, zqh, zql);
    out_mfma<<<dim3(128, 8), 256, 0, stream>>>(woh, wol, zqh, zql, out_b, out + OUT_ZQ);
    finalize_kernel<<<1, 256, 0, stream>>>(ws + WS_CNT, cluster, ws + WS_LOSS, out);
}